// Round 10
// baseline (865.367 us; speedup 1.0000x reference)
//
#include <hip/hip_runtime.h>
#include <cfloat>

// VectorQuantizer: N=32768 rows, K=8192 codes, D=256, fp32.
// R2/R3 (absmax 0): reference = numpy fp32; exact top-8 rescore of approx
// candidates reproduces it bit-for-bit.
// R6 (125.3us score): 64-row LDS dbuf + syncthreads.               MfmaUtil 22.5
// R10 (119.4us): barrier-free counted-vmcnt (no cross-wave flow).  MfmaUtil 24
// R12 (117.7us): + deferred SEL + B reg-prefetch.                  MfmaUtil 24.5
// R13 (447us): launch_bounds(256,3) clamped VGPR=84 -> total spill. Structure
//   (32-row blocks, keys, merge) verified absmax-0.
// R14 (281us): spill fixed (VGPR 108, WRITE 1024KB) but DIRECT strided-global
//   B: each load = 32 distinct 64B lines -> 256 line-transactions/wave-kt
//   through one TCP, L1-missing L2 latency stacks; MfmaUtil 9.9%. LESSON:
//   B needs the dense coalesced map + LDS shuffle; never strided gathers.
// R15: verified pieces only, recombined for TLP:
//   - 32-row blocks, grid 1024 (R13/R14-verified keys+merge).
//   - R6 dense staging map (0 conflicts), but REG-STAGED (T14): 8x uint4
//     dense loads/thread issued a full iteration ahead, then ds_write_b128
//     into a SINGLE 32KB buffer. R10's fact (wave stages+reads only its own
//     8KB quarter) + per-wave in-order LDS => WAR/RAW safe with NO barriers
//     and NO inline asm in the K-loop; compiler inserts vmcnt/lgkmcnt.
//   - LDS 32KB/block, arch regs ~140 -> 3-4 waves/SIMD (vs 2 all session).
// R16 (this round): R15 died to the session's 3rd infra flake ("container
//   failed twice", no counters); R7->R8 and R10->R11 precedents both ran fine
//   on identical resubmit. Hang audit clean: no K-loop barriers/asm waits,
//   uniform __syncthreads, bounds exact, staging<->read map re-derived
//   bit-identical to R6's. Resubmitted unchanged.
//   Tripwires: WRITE_SIZE must stay 1024KB; VGPR 130-160 expected.
// prep_w / rescore untouched (bit-exact verified).

#define DDIM 256

typedef int   i32x8  __attribute__((ext_vector_type(8)));
typedef float f32x16 __attribute__((ext_vector_type(16)));

// ---------- W prep: numpy-exact ||w||^2 + negated scaled fp8 ----------
__global__ __launch_bounds__(256) void vq_prep_w(
    const float* __restrict__ w, float* __restrict__ wn,
    unsigned char* __restrict__ wb8) {
    __shared__ float rows[32 * 260];
    const int tid = threadIdx.x;
    const int r0 = blockIdx.x * 32;

    for (int idx = tid; idx < 32 * 64; idx += 256) {
        int r = idx >> 6, c4 = idx & 63;
        *(float4*)&rows[r * 260 + c4 * 4] =
            *(const float4*)(w + (size_t)(r0 + r) * DDIM + c4 * 4);
    }
    __syncthreads();
    {
        // numpy pairwise_sum(fl(a*a),256): two 128-halves, each 8 stride-8
        // chains, ((r0+r1)+(r2+r3))+((r4+r5)+(r6+r7)); shfl-xor == nesting.
        const int row = (tid >> 6) * 8 + ((tid & 63) >> 3), j = tid & 7;
        const float* a = &rows[row * 260];
        float half[2];
#pragma unroll
        for (int h = 0; h < 2; ++h) {
            const float* b = a + h * 128 + j;
            float r = __fmul_rn(b[0], b[0]);
#pragma unroll
            for (int t = 1; t < 16; ++t)
                r = __fadd_rn(r, __fmul_rn(b[8 * t], b[8 * t]));
            float p = __fadd_rn(r, __shfl_xor(r, 1, 64));
            p = __fadd_rn(p, __shfl_xor(p, 2, 64));
            p = __fadd_rn(p, __shfl_xor(p, 4, 64));
            half[h] = p;
        }
        if (j == 0) wn[r0 + row] = __fadd_rn(half[0], half[1]);
    }
    // fp8 e4m3 emission, scaled by -2^13 (pow2 cancels in argmin; negation
    // folds the "-2m" sign so acc = C - m_s with C=128 init)
    for (int idx = tid; idx < 32 * 16; idx += 256) {
        int r = idx >> 4, s = idx & 15;
        const float* p = &rows[r * 260 + s * 16];
        unsigned q[4];
#pragma unroll
        for (int m = 0; m < 4; ++m) {
            unsigned v = (unsigned)__builtin_amdgcn_cvt_pk_fp8_f32(
                p[m * 4 + 0] * -8192.f, p[m * 4 + 1] * -8192.f, 0, false);
            v = (unsigned)__builtin_amdgcn_cvt_pk_fp8_f32(
                p[m * 4 + 2] * -8192.f, p[m * 4 + 3] * -8192.f, (int)v, true);
            q[m] = v;
        }
        *(uint4*)(wb8 + (size_t)(r0 + r) * DDIM + s * 16) =
            make_uint4(q[0], q[1], q[2], q[3]);
    }
}

// ---------- MX-fp8 scorer: 32 rows x 8192 cols per block ----------
// 256 thr = 4 waves (wave = 32-col group); per wave per kt: 4-MFMA chain
// (ks over D=256). A resident in VGPRs. W tile 128c x 256d = 32KB, SINGLE
// LDS buffer, reg-staged (dense map), barrier-free K-loop (per-wave private
// quarters + in-order LDS). LDS reused for the 32KB merge.
// C/D (32x32): col=lane&31, row=(reg&3)+8*(reg>>2)+4*(lane>>5)  [m74/m101].

#define INIT128(C) { _Pragma("unroll") for (int r_ = 0; r_ < 16; ++r_) (C)[r_] = 128.0f; }

// selection (R6-verbatim logic): acc = 128 - m_s > 0, uint-monotone;
// top-2 per (lane,reg) slot = code residue mod 128 per row.
#define SEL16(P, pkt) { \
    const unsigned colv_ = (unsigned)((pkt) * 128 + bcol); \
    _Pragma("unroll") for (int r_ = 0; r_ < 16; ++r_) { \
        unsigned key_ = (__float_as_uint((P)[r_]) & 0xFFFFE000u) | colv_; \
        unsigned a0_ = s0[r_]; \
        unsigned mx_ = key_ > a0_ ? key_ : a0_; \
        s1[r_] = mx_ < s1[r_] ? mx_ : s1[r_]; \
        s0[r_] = key_ < a0_ ? key_ : a0_; \
    } }

// dense-coalesced global loads of tile kt into registers (R6 map)
#define LOADS(kt) { \
    const unsigned char* g_ = wb8 + (size_t)(kt) * 32768; \
    _Pragma("unroll") for (int i_ = 0; i_ < 8; ++i_) \
        S[i_] = *(const uint4*)(g_ + sOfs[i_]); }

// registers -> LDS (each wave writes only its own 8KB quarter)
#define WRITES() { \
    _Pragma("unroll") for (int i_ = 0; i_ < 8; ++i_) \
        *(uint4*)(Ws + ldsOfs[i_]) = S[i_]; }

#define MFMA1(A, B) \
    acc = __builtin_amdgcn_mfma_scale_f32_32x32x64_f8f6f4( \
        A, B.v, acc, 0, 0, 0, 0x7F7F7F7F, 0, 0x7F7F7F7F)

__global__ __launch_bounds__(256) void vq_score(
    const float* __restrict__ x, const unsigned char* __restrict__ wb8,
    unsigned* __restrict__ cand) {
    __shared__ __align__(16) unsigned char Ws[32768];
    const int tid = threadIdx.x;
    const int wave = tid >> 6, lane = tid & 63;
    const int h = lane >> 5, c32 = lane & 31;
    const int rowBase = blockIdx.x * 32;
    const int bcol = wave * 32 + c32;

    // A fragments: 32 rows x 256 dims fp8 (row = c32), converted in-kernel.
    i32x8 af[4];
    {
        const float* xr = x + (size_t)(rowBase + c32) * DDIM;
#pragma unroll
        for (int ks = 0; ks < 4; ++ks) {
            const float4* p = (const float4*)(xr + ks * 64 + h * 32);
            union { int d[8]; i32x8 v; } u;
#pragma unroll
            for (int m = 0; m < 8; ++m) {
                float4 f = p[m];
                unsigned v = (unsigned)__builtin_amdgcn_cvt_pk_fp8_f32(
                    f.x, f.y, 0, false);
                v = (unsigned)__builtin_amdgcn_cvt_pk_fp8_f32(
                    f.z, f.w, (int)v, true);
                u.d[m] = (int)v;
            }
            af[ks] = u.v;
        }
    }

    // staging maps (R6 VERBATIM, dense): slot covers 4 cols; granule XOR-
    // placed by col&15; wave w stages cols w*32..+31 = exactly its read cols.
    // Lane l writes granule g=(l&15)^(col&15) of col to byte col*256+(l&15)*16
    // => granule g sits at col*256+(g^(col&15))*16, matching bofs below.
    unsigned sOfs[8], ldsOfs[8];
#pragma unroll
    for (int i = 0; i < 8; ++i) {
        int slot = wave * 8 + i;                  // 0..31
        int col  = slot * 4 + (lane >> 4);        // 0..127
        int gsrc = (lane & 15) ^ (col & 15);      // XOR bank spread
        sOfs[i]   = (unsigned)(col * 256 + gsrc * 16);
        ldsOfs[i] = (unsigned)(slot * 1024 + (lane << 4));
    }

    // B-fragment read offsets (R6 VERBATIM): granule gb of col bcol at
    // bcol*256 + (gb^(bcol&15))*16. Measured zero bank conflicts.
    const int cs = bcol & 15;
    int bofs[4][2];
#pragma unroll
    for (int ks = 0; ks < 4; ++ks) {
        int gb = ks * 4 + h * 2;
        bofs[ks][0] = bcol * 256 + ((gb)     ^ cs) * 16;
        bofs[ks][1] = bcol * 256 + ((gb + 1) ^ cs) * 16;
    }

    unsigned s0[16], s1[16];
#pragma unroll
    for (int r = 0; r < 16; ++r) { s0[r] = 0xFFFFFFFFu; s1[r] = 0xFFFFFFFFu; }

    f32x16 acc;
    uint4 S[8];

    // Single-buffer reg-staged pipeline (no barriers, no asm):
    //   prologue: S<-tile0; LDS<-S; S<-tile1 (in flight).
    //   iter kt: ds_read+MFMA (tile kt) -> [LDS<-S (tile kt+1): WAR ok,
    //   in-order per-wave LDS; S<-tile kt+2] -> SEL (hides write latency).
    //   Compiler inserts vmcnt before WRITES and lgkmcnt before MFMAs.
    LOADS(0);
    WRITES();
    LOADS(1);

    for (int kt = 0; kt < 64; ++kt) {
        INIT128(acc);
        __builtin_amdgcn_s_setprio(1);
#pragma unroll
        for (int ks = 0; ks < 4; ++ks) {
            union { uint4 q[2]; i32x8 v; } b_;
            b_.q[0] = *(const uint4*)(Ws + bofs[ks][0]);
            b_.q[1] = *(const uint4*)(Ws + bofs[ks][1]);
            MFMA1(af[ks], b_);
        }
        __builtin_amdgcn_s_setprio(0);
        if (kt < 63) {
            WRITES();                       // LDS <- tile kt+1
            if (kt < 62) LOADS(kt + 2);     // S <- tile kt+2 (dense, 1 iter lead)
        }
        SEL16(acc, kt);
    }

    // merge: 32 rows x 256 keys = 32 KB (reuse Ws); first cross-wave flow
    __syncthreads();
    unsigned* ms = (unsigned*)Ws;
#pragma unroll
    for (int r = 0; r < 16; ++r) {
        int rloc = (r & 3) + 8 * (r >> 2) + 4 * h;
        *(uint2*)&ms[rloc * 256 + bcol * 2] = make_uint2(s0[r], s1[r]);
    }
    __syncthreads();
    if (tid < 32) {
        const uint4* rowk = (const uint4*)(ms + tid * 256);
        unsigned best[8];
#pragma unroll
        for (int i = 0; i < 8; ++i) best[i] = 0xFFFFFFFFu;
        for (int i = 0; i < 64; ++i) {
            uint4 qv = rowk[(i + tid) & 63];   // rotated: bank spread
            unsigned kk[4] = {qv.x, qv.y, qv.z, qv.w};
#pragma unroll
            for (int e = 0; e < 4; ++e) {
                unsigned key = kk[e];
                if (key < best[7]) {
                    best[7] = key;
#pragma unroll
                    for (int j = 7; j > 0; --j)
                        if (best[j] < best[j - 1]) {
                            unsigned t = best[j]; best[j] = best[j - 1]; best[j - 1] = t;
                        }
                }
            }
        }
        unsigned* out = cand + (size_t)(rowBase + tid) * 8;
#pragma unroll
        for (int i = 0; i < 8; ++i) out[i] = best[i];
    }
}

// ---------- exact rescore (fp32 chain, R3-verified) + inline numpy x2 ----------
__global__ __launch_bounds__(256) void vq_rescore_write(
    const float* __restrict__ x, const float* __restrict__ w,
    const float* __restrict__ wn, const unsigned* __restrict__ cand,
    float* __restrict__ outq, float* __restrict__ outi) {
    __shared__ int winners[32];
    const int tid = threadIdx.x;
    const int lr = tid >> 3, cc = tid & 7;
    const int row = blockIdx.x * 32 + lr;

    int k = (int)(cand[(size_t)row * 8 + cc] & 0x1FFFu);
    const float* xr = x + (size_t)row * DDIM;
    const float* wr = w + (size_t)k * DDIM;
    // dot: single fp32 fmaf chain d-ascending (BLAS-exact, R2/R3-verified)
    // x2: numpy pairwise (two halves, 8 stride-8 chains, exact nesting)
    float dot = 0.f;
    float half[2];
#pragma unroll
    for (int hh = 0; hh < 2; ++hh) {
        float r[8];
#pragma unroll
        for (int t = 0; t < 16; ++t) {
            const int d = hh * 128 + t * 8;
            float4 xa = *(const float4*)(xr + d);
            float4 xb = *(const float4*)(xr + d + 4);
            float4 wa = *(const float4*)(wr + d);
            float4 wb = *(const float4*)(wr + d + 4);
            dot = __fmaf_rn(xa.x, wa.x, dot); dot = __fmaf_rn(xa.y, wa.y, dot);
            dot = __fmaf_rn(xa.z, wa.z, dot); dot = __fmaf_rn(xa.w, wa.w, dot);
            dot = __fmaf_rn(xb.x, wb.x, dot); dot = __fmaf_rn(xb.y, wb.y, dot);
            dot = __fmaf_rn(xb.z, wb.z, dot); dot = __fmaf_rn(xb.w, wb.w, dot);
            if (t == 0) {
                r[0] = __fmul_rn(xa.x, xa.x); r[1] = __fmul_rn(xa.y, xa.y);
                r[2] = __fmul_rn(xa.z, xa.z); r[3] = __fmul_rn(xa.w, xa.w);
                r[4] = __fmul_rn(xb.x, xb.x); r[5] = __fmul_rn(xb.y, xb.y);
                r[6] = __fmul_rn(xb.z, xb.z); r[7] = __fmul_rn(xb.w, xb.w);
            } else {
                r[0] = __fadd_rn(r[0], __fmul_rn(xa.x, xa.x));
                r[1] = __fadd_rn(r[1], __fmul_rn(xa.y, xa.y));
                r[2] = __fadd_rn(r[2], __fmul_rn(xa.z, xa.z));
                r[3] = __fadd_rn(r[3], __fmul_rn(xa.w, xa.w));
                r[4] = __fadd_rn(r[4], __fmul_rn(xb.x, xb.x));
                r[5] = __fadd_rn(r[5], __fmul_rn(xb.y, xb.y));
                r[6] = __fadd_rn(r[6], __fmul_rn(xb.w == xb.w ? xb.z : xb.z, xb.z));
                r[7] = __fadd_rn(r[7], __fmul_rn(xb.w, xb.w));
            }
        }
        half[hh] = __fadd_rn(__fadd_rn(__fadd_rn(r[0], r[1]), __fadd_rn(r[2], r[3])),
                             __fadd_rn(__fadd_rn(r[4], r[5]), __fadd_rn(r[6], r[7])));
    }
    float x2v = __fadd_rn(half[0], half[1]);
    float dv = __fsub_rn(__fadd_rn(x2v, wn[k]), __fmul_rn(2.0f, dot));
    // lexicographic (dv,k) min across 8 candidate lanes (first-occurrence)
#pragma unroll
    for (int m = 1; m < 8; m <<= 1) {
        float od = __shfl_xor(dv, m, 64);
        int   ok = __shfl_xor(k,  m, 64);
        if (od < dv || (od == dv && ok < k)) { dv = od; k = ok; }
    }
    if (cc == 0) winners[lr] = k;
    __syncthreads();
    if (tid < 32) outi[blockIdx.x * 32 + tid] = (float)winners[tid];
    for (int u = tid; u < 32 * 64; u += 256) {
        int r = u >> 6, c4 = u & 63;
        *reinterpret_cast<float4*>(outq + (size_t)(blockIdx.x * 32 + r) * DDIM + c4 * 4) =
            *reinterpret_cast<const float4*>(w + (size_t)winners[r] * DDIM + c4 * 4);
    }
}

extern "C" void kernel_launch(void* const* d_in, const int* in_sizes, int n_in,
                              void* d_out, int out_size, void* d_ws, size_t ws_size,
                              hipStream_t stream) {
    const float* x = (const float*)d_in[0];
    const float* w = (const float*)d_in[1];
    const int N = in_sizes[0] / DDIM;   // 32768
    const int K = in_sizes[1] / DDIM;   // 8192
    float* outq = (float*)d_out;
    float* outi = outq + (size_t)N * DDIM;

    unsigned char* wb8 = (unsigned char*)d_ws;                // K*256 = 2 MB
    float* wn = (float*)(wb8 + (size_t)K * DDIM);             // K floats
    unsigned* cand = (unsigned*)(wn + K);                     // N*8 u32 = 1 MB

    hipLaunchKernelGGL(vq_prep_w, dim3(K / 32), dim3(256), 0, stream, w, wn, wb8);
    hipLaunchKernelGGL(vq_score, dim3(N / 32), dim3(256), 0, stream, x, wb8, cand);
    hipLaunchKernelGGL(vq_rescore_write, dim3(N / 32), dim3(256), 0, stream,
                       x, w, wn, cand, outq, outi);
}

// Round 11
// 821.669 us; speedup vs baseline: 1.0532x; 1.0532x over previous
//
#include <hip/hip_runtime.h>
#include <cfloat>

// VectorQuantizer: N=32768 rows, K=8192 codes, D=256, fp32.
// R2/R3 (absmax 0): reference = numpy fp32; exact top-8 rescore of approx
// candidates reproduces it bit-for-bit.
// R6 (125.3us score): 64-row LDS dbuf + syncthreads.               MfmaUtil 22.5
// R10 (119.4us): barrier-free counted-vmcnt (no cross-wave flow).  MfmaUtil 24
// R12 (117.7us): + deferred SEL + B reg-prefetch.                  MfmaUtil 24.5
//   => latency-bound at 2 waves/SIMD; three schedules, same ~4400cy/kt wall.
// R13 (447us): launch_bounds(256,3) -> VGPR cap 84 -> total spill.
// R14 (281us): direct strided-global B = 32 lines/instr -> TCP-serialized L2
//   latency stacks. LESSON: B must go dense-coalesced + LDS shuffle.
// R15/R16 (765us): reg-staged single-buffer 32KB structure CORRECT (absmax 0)
//   but PLAIN launch_bounds let the heuristic pick cap 84 -> 1.55GB scratch.
//   VGPR-cap map now complete: (256,2)->128 safe; (256,3)->84; plain->108|84
//   (structure-dependent gamble).
// R18 (this round): R15 verbatim + __launch_bounds__(256,2) (the one reliable
//   cap: 128, never spilled in R6-R12) + reg micro-trim (ldsOfs array ->
//   base + compile-time imm, folds into ds_write offsets).
//   With 32KB LDS/block, occupancy is VGPR-limited: VGPR<=128 -> 4 waves/SIMD,
//   LDS allows 5 blocks/CU, grid 1024 = 4x256 -> 4 blocks/CU co-resident =
//   16 waves/CU, DOUBLE the session's TLP. R6-R12 carried more state at
//   104-124 regs (accs land in unified AGPRs), so this fits.
//   Tripwires: WRITE_SIZE must stay 1024KB; VGPR<=128; Occupancy ~35-50%.
// prep_w / rescore untouched (bit-exact verified).

#define DDIM 256

typedef int   i32x8  __attribute__((ext_vector_type(8)));
typedef float f32x16 __attribute__((ext_vector_type(16)));

// ---------- W prep: numpy-exact ||w||^2 + negated scaled fp8 ----------
__global__ __launch_bounds__(256) void vq_prep_w(
    const float* __restrict__ w, float* __restrict__ wn,
    unsigned char* __restrict__ wb8) {
    __shared__ float rows[32 * 260];
    const int tid = threadIdx.x;
    const int r0 = blockIdx.x * 32;

    for (int idx = tid; idx < 32 * 64; idx += 256) {
        int r = idx >> 6, c4 = idx & 63;
        *(float4*)&rows[r * 260 + c4 * 4] =
            *(const float4*)(w + (size_t)(r0 + r) * DDIM + c4 * 4);
    }
    __syncthreads();
    {
        // numpy pairwise_sum(fl(a*a),256): two 128-halves, each 8 stride-8
        // chains, ((r0+r1)+(r2+r3))+((r4+r5)+(r6+r7)); shfl-xor == nesting.
        const int row = (tid >> 6) * 8 + ((tid & 63) >> 3), j = tid & 7;
        const float* a = &rows[row * 260];
        float half[2];
#pragma unroll
        for (int h = 0; h < 2; ++h) {
            const float* b = a + h * 128 + j;
            float r = __fmul_rn(b[0], b[0]);
#pragma unroll
            for (int t = 1; t < 16; ++t)
                r = __fadd_rn(r, __fmul_rn(b[8 * t], b[8 * t]));
            float p = __fadd_rn(r, __shfl_xor(r, 1, 64));
            p = __fadd_rn(p, __shfl_xor(p, 2, 64));
            p = __fadd_rn(p, __shfl_xor(p, 4, 64));
            half[h] = p;
        }
        if (j == 0) wn[r0 + row] = __fadd_rn(half[0], half[1]);
    }
    // fp8 e4m3 emission, scaled by -2^13 (pow2 cancels in argmin; negation
    // folds the "-2m" sign so acc = C - m_s with C=128 init)
    for (int idx = tid; idx < 32 * 16; idx += 256) {
        int r = idx >> 4, s = idx & 15;
        const float* p = &rows[r * 260 + s * 16];
        unsigned q[4];
#pragma unroll
        for (int m = 0; m < 4; ++m) {
            unsigned v = (unsigned)__builtin_amdgcn_cvt_pk_fp8_f32(
                p[m * 4 + 0] * -8192.f, p[m * 4 + 1] * -8192.f, 0, false);
            v = (unsigned)__builtin_amdgcn_cvt_pk_fp8_f32(
                p[m * 4 + 2] * -8192.f, p[m * 4 + 3] * -8192.f, (int)v, true);
            q[m] = v;
        }
        *(uint4*)(wb8 + (size_t)(r0 + r) * DDIM + s * 16) =
            make_uint4(q[0], q[1], q[2], q[3]);
    }
}

// ---------- MX-fp8 scorer: 32 rows x 8192 cols per block, 4 blocks/CU ----------
// 256 thr = 4 waves (wave = 32-col group); per wave per kt: 4-MFMA chain
// (ks over D=256). A resident in VGPRs. W tile 128c x 256d = 32KB, SINGLE
// LDS buffer, reg-staged (dense map), barrier-free K-loop (per-wave private
// quarters + in-order LDS). LDS reused for the 32KB merge.
// C/D (32x32): col=lane&31, row=(reg&3)+8*(reg>>2)+4*(lane>>5)  [m74/m101].

#define INIT128(C) { _Pragma("unroll") for (int r_ = 0; r_ < 16; ++r_) (C)[r_] = 128.0f; }

// selection (R6-verbatim logic): acc = 128 - m_s > 0, uint-monotone;
// top-2 per (lane,reg) slot = code residue mod 128 per row.
#define SEL16(P, pkt) { \
    const unsigned colv_ = (unsigned)((pkt) * 128 + bcol); \
    _Pragma("unroll") for (int r_ = 0; r_ < 16; ++r_) { \
        unsigned key_ = (__float_as_uint((P)[r_]) & 0xFFFFE000u) | colv_; \
        unsigned a0_ = s0[r_]; \
        unsigned mx_ = key_ > a0_ ? key_ : a0_; \
        s1[r_] = mx_ < s1[r_] ? mx_ : s1[r_]; \
        s0[r_] = key_ < a0_ ? key_ : a0_; \
    } }

// dense-coalesced global loads of tile kt into registers (R6 map)
#define LOADS(kt) { \
    const unsigned char* g_ = wb8 + (size_t)(kt) * 32768; \
    _Pragma("unroll") for (int i_ = 0; i_ < 8; ++i_) \
        S[i_] = *(const uint4*)(g_ + sOfs[i_]); }

// registers -> LDS (each wave writes only its own 8KB quarter; i*1024 is a
// compile-time immediate -> folds into the ds_write encoding, no VGPR)
#define WRITES() { \
    _Pragma("unroll") for (int i_ = 0; i_ < 8; ++i_) \
        *(uint4*)(Ws + ldsBase + i_ * 1024) = S[i_]; }

#define MFMA1(A, B) \
    acc = __builtin_amdgcn_mfma_scale_f32_32x32x64_f8f6f4( \
        A, B.v, acc, 0, 0, 0, 0x7F7F7F7F, 0, 0x7F7F7F7F)

__global__ __launch_bounds__(256, 2) void vq_score(
    const float* __restrict__ x, const unsigned char* __restrict__ wb8,
    unsigned* __restrict__ cand) {
    __shared__ __align__(16) unsigned char Ws[32768];
    const int tid = threadIdx.x;
    const int wave = tid >> 6, lane = tid & 63;
    const int h = lane >> 5, c32 = lane & 31;
    const int rowBase = blockIdx.x * 32;
    const int bcol = wave * 32 + c32;

    // A fragments: 32 rows x 256 dims fp8 (row = c32), converted in-kernel.
    i32x8 af[4];
    {
        const float* xr = x + (size_t)(rowBase + c32) * DDIM;
#pragma unroll
        for (int ks = 0; ks < 4; ++ks) {
            const float4* p = (const float4*)(xr + ks * 64 + h * 32);
            union { int d[8]; i32x8 v; } u;
#pragma unroll
            for (int m = 0; m < 8; ++m) {
                float4 f = p[m];
                unsigned v = (unsigned)__builtin_amdgcn_cvt_pk_fp8_f32(
                    f.x, f.y, 0, false);
                v = (unsigned)__builtin_amdgcn_cvt_pk_fp8_f32(
                    f.z, f.w, (int)v, true);
                u.d[m] = (int)v;
            }
            af[ks] = u.v;
        }
    }

    // staging maps (R6 VERBATIM, dense): slot covers 4 cols; granule XOR-
    // placed by col&15; wave w stages cols w*32..+31 = exactly its read cols.
    // Lane l writes granule g=(l&15)^(col&15) of col to byte col*256+(l&15)*16
    // => granule g sits at col*256+(g^(col&15))*16, matching bofs below.
    unsigned sOfs[8];
#pragma unroll
    for (int i = 0; i < 8; ++i) {
        int slot = wave * 8 + i;                  // 0..31
        int col  = slot * 4 + (lane >> 4);        // 0..127
        int gsrc = (lane & 15) ^ (col & 15);      // XOR bank spread
        sOfs[i] = (unsigned)(col * 256 + gsrc * 16);
    }
    const unsigned ldsBase = (unsigned)(wave * 8192 + (lane << 4));

    // B-fragment read offsets (R6 VERBATIM): granule gb of col bcol at
    // bcol*256 + (gb^(bcol&15))*16. Measured zero bank conflicts.
    const int cs = bcol & 15;
    int bofs[4][2];
#pragma unroll
    for (int ks = 0; ks < 4; ++ks) {
        int gb = ks * 4 + h * 2;
        bofs[ks][0] = bcol * 256 + ((gb)     ^ cs) * 16;
        bofs[ks][1] = bcol * 256 + ((gb + 1) ^ cs) * 16;
    }

    unsigned s0[16], s1[16];
#pragma unroll
    for (int r = 0; r < 16; ++r) { s0[r] = 0xFFFFFFFFu; s1[r] = 0xFFFFFFFFu; }

    f32x16 acc;
    uint4 S[8];

    // Single-buffer reg-staged pipeline (no barriers, no asm):
    //   prologue: S<-tile0; LDS<-S; S<-tile1 (in flight).
    //   iter kt: ds_read+MFMA (tile kt) -> [LDS<-S (tile kt+1): WAR ok,
    //   in-order per-wave LDS; S<-tile kt+2] -> SEL (hides write latency).
    //   Compiler inserts vmcnt before WRITES and lgkmcnt before MFMAs.
    LOADS(0);
    WRITES();
    LOADS(1);

    for (int kt = 0; kt < 64; ++kt) {
        INIT128(acc);
        __builtin_amdgcn_s_setprio(1);
#pragma unroll
        for (int ks = 0; ks < 4; ++ks) {
            union { uint4 q[2]; i32x8 v; } b_;
            b_.q[0] = *(const uint4*)(Ws + bofs[ks][0]);
            b_.q[1] = *(const uint4*)(Ws + bofs[ks][1]);
            MFMA1(af[ks], b_);
        }
        __builtin_amdgcn_s_setprio(0);
        if (kt < 63) {
            WRITES();                       // LDS <- tile kt+1
            if (kt < 62) LOADS(kt + 2);     // S <- tile kt+2 (dense, 1 iter lead)
        }
        SEL16(acc, kt);
    }

    // merge: 32 rows x 256 keys = 32 KB (reuse Ws); first cross-wave flow
    __syncthreads();
    unsigned* ms = (unsigned*)Ws;
#pragma unroll
    for (int r = 0; r < 16; ++r) {
        int rloc = (r & 3) + 8 * (r >> 2) + 4 * h;
        *(uint2*)&ms[rloc * 256 + bcol * 2] = make_uint2(s0[r], s1[r]);
    }
    __syncthreads();
    if (tid < 32) {
        const uint4* rowk = (const uint4*)(ms + tid * 256);
        unsigned best[8];
#pragma unroll
        for (int i = 0; i < 8; ++i) best[i] = 0xFFFFFFFFu;
        for (int i = 0; i < 64; ++i) {
            uint4 qv = rowk[(i + tid) & 63];   // rotated: bank spread
            unsigned kk[4] = {qv.x, qv.y, qv.z, qv.w};
#pragma unroll
            for (int e = 0; e < 4; ++e) {
                unsigned key = kk[e];
                if (key < best[7]) {
                    best[7] = key;
#pragma unroll
                    for (int j = 7; j > 0; --j)
                        if (best[j] < best[j - 1]) {
                            unsigned t = best[j]; best[j] = best[j - 1]; best[j - 1] = t;
                        }
                }
            }
        }
        unsigned* out = cand + (size_t)(rowBase + tid) * 8;
#pragma unroll
        for (int i = 0; i < 8; ++i) out[i] = best[i];
    }
}

// ---------- exact rescore (fp32 chain, R3-verified) + inline numpy x2 ----------
__global__ __launch_bounds__(256) void vq_rescore_write(
    const float* __restrict__ x, const float* __restrict__ w,
    const float* __restrict__ wn, const unsigned* __restrict__ cand,
    float* __restrict__ outq, float* __restrict__ outi) {
    __shared__ int winners[32];
    const int tid = threadIdx.x;
    const int lr = tid >> 3, cc = tid & 7;
    const int row = blockIdx.x * 32 + lr;

    int k = (int)(cand[(size_t)row * 8 + cc] & 0x1FFFu);
    const float* xr = x + (size_t)row * DDIM;
    const float* wr = w + (size_t)k * DDIM;
    // dot: single fp32 fmaf chain d-ascending (BLAS-exact, R2/R3-verified)
    // x2: numpy pairwise (two halves, 8 stride-8 chains, exact nesting)
    float dot = 0.f;
    float half[2];
#pragma unroll
    for (int hh = 0; hh < 2; ++hh) {
        float r[8];
#pragma unroll
        for (int t = 0; t < 16; ++t) {
            const int d = hh * 128 + t * 8;
            float4 xa = *(const float4*)(xr + d);
            float4 xb = *(const float4*)(xr + d + 4);
            float4 wa = *(const float4*)(wr + d);
            float4 wb = *(const float4*)(wr + d + 4);
            dot = __fmaf_rn(xa.x, wa.x, dot); dot = __fmaf_rn(xa.y, wa.y, dot);
            dot = __fmaf_rn(xa.z, wa.z, dot); dot = __fmaf_rn(xa.w, wa.w, dot);
            dot = __fmaf_rn(xb.x, wb.x, dot); dot = __fmaf_rn(xb.y, wb.y, dot);
            dot = __fmaf_rn(xb.z, wb.z, dot); dot = __fmaf_rn(xb.w, wb.w, dot);
            if (t == 0) {
                r[0] = __fmul_rn(xa.x, xa.x); r[1] = __fmul_rn(xa.y, xa.y);
                r[2] = __fmul_rn(xa.z, xa.z); r[3] = __fmul_rn(xa.w, xa.w);
                r[4] = __fmul_rn(xb.x, xb.x); r[5] = __fmul_rn(xb.y, xb.y);
                r[6] = __fmul_rn(xb.z, xb.z); r[7] = __fmul_rn(xb.w, xb.w);
            } else {
                r[0] = __fadd_rn(r[0], __fmul_rn(xa.x, xa.x));
                r[1] = __fadd_rn(r[1], __fmul_rn(xa.y, xa.y));
                r[2] = __fadd_rn(r[2], __fmul_rn(xa.z, xa.z));
                r[3] = __fadd_rn(r[3], __fmul_rn(xa.w, xa.w));
                r[4] = __fadd_rn(r[4], __fmul_rn(xb.x, xb.x));
                r[5] = __fadd_rn(r[5], __fmul_rn(xb.y, xb.y));
                r[6] = __fadd_rn(r[6], __fmul_rn(xb.w == xb.w ? xb.z : xb.z, xb.z));
                r[7] = __fadd_rn(r[7], __fmul_rn(xb.w, xb.w));
            }
        }
        half[hh] = __fadd_rn(__fadd_rn(__fadd_rn(r[0], r[1]), __fadd_rn(r[2], r[3])),
                             __fadd_rn(__fadd_rn(r[4], r[5]), __fadd_rn(r[6], r[7])));
    }
    float x2v = __fadd_rn(half[0], half[1]);
    float dv = __fsub_rn(__fadd_rn(x2v, wn[k]), __fmul_rn(2.0f, dot));
    // lexicographic (dv,k) min across 8 candidate lanes (first-occurrence)
#pragma unroll
    for (int m = 1; m < 8; m <<= 1) {
        float od = __shfl_xor(dv, m, 64);
        int   ok = __shfl_xor(k,  m, 64);
        if (od < dv || (od == dv && ok < k)) { dv = od; k = ok; }
    }
    if (cc == 0) winners[lr] = k;
    __syncthreads();
    if (tid < 32) outi[blockIdx.x * 32 + tid] = (float)winners[tid];
    for (int u = tid; u < 32 * 64; u += 256) {
        int r = u >> 6, c4 = u & 63;
        *reinterpret_cast<float4*>(outq + (size_t)(blockIdx.x * 32 + r) * DDIM + c4 * 4) =
            *reinterpret_cast<const float4*>(w + (size_t)winners[r] * DDIM + c4 * 4);
    }
}

extern "C" void kernel_launch(void* const* d_in, const int* in_sizes, int n_in,
                              void* d_out, int out_size, void* d_ws, size_t ws_size,
                              hipStream_t stream) {
    const float* x = (const float*)d_in[0];
    const float* w = (const float*)d_in[1];
    const int N = in_sizes[0] / DDIM;   // 32768
    const int K = in_sizes[1] / DDIM;   // 8192
    float* outq = (float*)d_out;
    float* outi = outq + (size_t)N * DDIM;

    unsigned char* wb8 = (unsigned char*)d_ws;                // K*256 = 2 MB
    float* wn = (float*)(wb8 + (size_t)K * DDIM);             // K floats
    unsigned* cand = (unsigned*)(wn + K);                     // N*8 u32 = 1 MB

    hipLaunchKernelGGL(vq_prep_w, dim3(K / 32), dim3(256), 0, stream, w, wn, wb8);
    hipLaunchKernelGGL(vq_score, dim3(N / 32), dim3(256), 0, stream, x, wb8, cand);
    hipLaunchKernelGGL(vq_rescore_write, dim3(N / 32), dim3(256), 0, stream,
                       x, w, wn, cand, outq, outi);
}

// Round 12
// 816.171 us; speedup vs baseline: 1.0603x; 1.0067x over previous
//
#include <hip/hip_runtime.h>
#include <cfloat>

// VectorQuantizer: N=32768 rows, K=8192 codes, D=256, fp32.
// R2/R3 (absmax 0): reference = numpy fp32; exact top-8 rescore of approx
// candidates reproduces it bit-for-bit.
// R6 (125.3us score): 64-row LDS dbuf + syncthreads.               MfmaUtil 22.5
// R10 (119.4us): barrier-free counted-vmcnt (no cross-wave flow).  MfmaUtil 24
// R12 (117.7us): + deferred SEL + B reg-prefetch.                  MfmaUtil 24.5
//   => latency-bound at 2 waves/SIMD; three schedules, same ~4400cy/kt wall.
// R13 (447us): launch_bounds(256,3) -> cap 84 -> spill.
// R14 (281us): direct strided-global B -> TCP-serialized L2 latency. LESSON:
//   B must go dense-coalesced + LDS shuffle.
// R15/R16 (765us): reg-staged single-32KB-buffer structure CORRECT (absmax 0)
//   but heuristic picked 84 regs -> 1.55GB scratch.
// R18 (704us): (256,2) did NOT restore 104-124 regs: VGPR=80, spill again.
//   MODEL COMPLETE: launch_bounds' 2nd arg only FLOORS occupancy (ceils regs);
//   the allocator's occupancy HEURISTIC picks the actual target and for this
//   32-row kernel insists on 6 waves/EU (80 regs) regardless. R6-R12 escaped
//   only because 64-row pressure pushed the heuristic to 2-3 waves.
// R19 (this round): pin the heuristic: __attribute__((amdgpu_waves_per_eu(3,3)))
//   min=3 -> budget 512/3~170 regs (structure needs ~140); max=3 -> heuristic
//   CANNOT target 6 waves. Code otherwise R18 verbatim (absmax-0-verified 3x).
//   3 waves/SIMD = 12 waves/CU = 3 blocks/CU (LDS 96KB<=160KB): +50% TLP over
//   every ~118us round. THE TLP experiment, finally actually run.
//   Tripwires: VGPR 140-170 (80 => attribute ignored, abandon path);
//   WRITE_SIZE == 1024KB exactly; Occupancy ~35%.
// prep_w / rescore untouched (bit-exact verified).

#define DDIM 256

typedef int   i32x8  __attribute__((ext_vector_type(8)));
typedef float f32x16 __attribute__((ext_vector_type(16)));

// ---------- W prep: numpy-exact ||w||^2 + negated scaled fp8 ----------
__global__ __launch_bounds__(256) void vq_prep_w(
    const float* __restrict__ w, float* __restrict__ wn,
    unsigned char* __restrict__ wb8) {
    __shared__ float rows[32 * 260];
    const int tid = threadIdx.x;
    const int r0 = blockIdx.x * 32;

    for (int idx = tid; idx < 32 * 64; idx += 256) {
        int r = idx >> 6, c4 = idx & 63;
        *(float4*)&rows[r * 260 + c4 * 4] =
            *(const float4*)(w + (size_t)(r0 + r) * DDIM + c4 * 4);
    }
    __syncthreads();
    {
        // numpy pairwise_sum(fl(a*a),256): two 128-halves, each 8 stride-8
        // chains, ((r0+r1)+(r2+r3))+((r4+r5)+(r6+r7)); shfl-xor == nesting.
        const int row = (tid >> 6) * 8 + ((tid & 63) >> 3), j = tid & 7;
        const float* a = &rows[row * 260];
        float half[2];
#pragma unroll
        for (int h = 0; h < 2; ++h) {
            const float* b = a + h * 128 + j;
            float r = __fmul_rn(b[0], b[0]);
#pragma unroll
            for (int t = 1; t < 16; ++t)
                r = __fadd_rn(r, __fmul_rn(b[8 * t], b[8 * t]));
            float p = __fadd_rn(r, __shfl_xor(r, 1, 64));
            p = __fadd_rn(p, __shfl_xor(p, 2, 64));
            p = __fadd_rn(p, __shfl_xor(p, 4, 64));
            half[h] = p;
        }
        if (j == 0) wn[r0 + row] = __fadd_rn(half[0], half[1]);
    }
    // fp8 e4m3 emission, scaled by -2^13 (pow2 cancels in argmin; negation
    // folds the "-2m" sign so acc = C - m_s with C=128 init)
    for (int idx = tid; idx < 32 * 16; idx += 256) {
        int r = idx >> 4, s = idx & 15;
        const float* p = &rows[r * 260 + s * 16];
        unsigned q[4];
#pragma unroll
        for (int m = 0; m < 4; ++m) {
            unsigned v = (unsigned)__builtin_amdgcn_cvt_pk_fp8_f32(
                p[m * 4 + 0] * -8192.f, p[m * 4 + 1] * -8192.f, 0, false);
            v = (unsigned)__builtin_amdgcn_cvt_pk_fp8_f32(
                p[m * 4 + 2] * -8192.f, p[m * 4 + 3] * -8192.f, (int)v, true);
            q[m] = v;
        }
        *(uint4*)(wb8 + (size_t)(r0 + r) * DDIM + s * 16) =
            make_uint4(q[0], q[1], q[2], q[3]);
    }
}

// ---------- MX-fp8 scorer: 32 rows x 8192 cols per block, 3 blocks/CU ----------
// 256 thr = 4 waves (wave = 32-col group); per wave per kt: 4-MFMA chain
// (ks over D=256). A resident in VGPRs. W tile 128c x 256d = 32KB, SINGLE
// LDS buffer, reg-staged (dense map), barrier-free K-loop (per-wave private
// quarters + in-order LDS). LDS reused for the 32KB merge.
// C/D (32x32): col=lane&31, row=(reg&3)+8*(reg>>2)+4*(lane>>5)  [m74/m101].

#define INIT128(C) { _Pragma("unroll") for (int r_ = 0; r_ < 16; ++r_) (C)[r_] = 128.0f; }

// selection (R6-verbatim logic): acc = 128 - m_s > 0, uint-monotone;
// top-2 per (lane,reg) slot = code residue mod 128 per row.
#define SEL16(P, pkt) { \
    const unsigned colv_ = (unsigned)((pkt) * 128 + bcol); \
    _Pragma("unroll") for (int r_ = 0; r_ < 16; ++r_) { \
        unsigned key_ = (__float_as_uint((P)[r_]) & 0xFFFFE000u) | colv_; \
        unsigned a0_ = s0[r_]; \
        unsigned mx_ = key_ > a0_ ? key_ : a0_; \
        s1[r_] = mx_ < s1[r_] ? mx_ : s1[r_]; \
        s0[r_] = key_ < a0_ ? key_ : a0_; \
    } }

// dense-coalesced global loads of tile kt into registers (R6 map)
#define LOADS(kt) { \
    const unsigned char* g_ = wb8 + (size_t)(kt) * 32768; \
    _Pragma("unroll") for (int i_ = 0; i_ < 8; ++i_) \
        S[i_] = *(const uint4*)(g_ + sOfs[i_]); }

// registers -> LDS (each wave writes only its own 8KB quarter; i*1024 is a
// compile-time immediate -> folds into the ds_write encoding, no VGPR)
#define WRITES() { \
    _Pragma("unroll") for (int i_ = 0; i_ < 8; ++i_) \
        *(uint4*)(Ws + ldsBase + i_ * 1024) = S[i_]; }

#define MFMA1(A, B) \
    acc = __builtin_amdgcn_mfma_scale_f32_32x32x64_f8f6f4( \
        A, B.v, acc, 0, 0, 0, 0x7F7F7F7F, 0, 0x7F7F7F7F)

__global__ __launch_bounds__(256)
__attribute__((amdgpu_waves_per_eu(3, 3)))
void vq_score(
    const float* __restrict__ x, const unsigned char* __restrict__ wb8,
    unsigned* __restrict__ cand) {
    __shared__ __align__(16) unsigned char Ws[32768];
    const int tid = threadIdx.x;
    const int wave = tid >> 6, lane = tid & 63;
    const int h = lane >> 5, c32 = lane & 31;
    const int rowBase = blockIdx.x * 32;
    const int bcol = wave * 32 + c32;

    // A fragments: 32 rows x 256 dims fp8 (row = c32), converted in-kernel.
    i32x8 af[4];
    {
        const float* xr = x + (size_t)(rowBase + c32) * DDIM;
#pragma unroll
        for (int ks = 0; ks < 4; ++ks) {
            const float4* p = (const float4*)(xr + ks * 64 + h * 32);
            union { int d[8]; i32x8 v; } u;
#pragma unroll
            for (int m = 0; m < 8; ++m) {
                float4 f = p[m];
                unsigned v = (unsigned)__builtin_amdgcn_cvt_pk_fp8_f32(
                    f.x, f.y, 0, false);
                v = (unsigned)__builtin_amdgcn_cvt_pk_fp8_f32(
                    f.z, f.w, (int)v, true);
                u.d[m] = (int)v;
            }
            af[ks] = u.v;
        }
    }

    // staging maps (R6 VERBATIM, dense): slot covers 4 cols; granule XOR-
    // placed by col&15; wave w stages cols w*32..+31 = exactly its read cols.
    // Lane l writes granule g=(l&15)^(col&15) of col to byte col*256+(l&15)*16
    // => granule g sits at col*256+(g^(col&15))*16, matching bofs below.
    unsigned sOfs[8];
#pragma unroll
    for (int i = 0; i < 8; ++i) {
        int slot = wave * 8 + i;                  // 0..31
        int col  = slot * 4 + (lane >> 4);        // 0..127
        int gsrc = (lane & 15) ^ (col & 15);      // XOR bank spread
        sOfs[i] = (unsigned)(col * 256 + gsrc * 16);
    }
    const unsigned ldsBase = (unsigned)(wave * 8192 + (lane << 4));

    // B-fragment read offsets (R6 VERBATIM): granule gb of col bcol at
    // bcol*256 + (gb^(bcol&15))*16. Measured zero bank conflicts.
    const int cs = bcol & 15;
    int bofs[4][2];
#pragma unroll
    for (int ks = 0; ks < 4; ++ks) {
        int gb = ks * 4 + h * 2;
        bofs[ks][0] = bcol * 256 + ((gb)     ^ cs) * 16;
        bofs[ks][1] = bcol * 256 + ((gb + 1) ^ cs) * 16;
    }

    unsigned s0[16], s1[16];
#pragma unroll
    for (int r = 0; r < 16; ++r) { s0[r] = 0xFFFFFFFFu; s1[r] = 0xFFFFFFFFu; }

    f32x16 acc;
    uint4 S[8];

    // Single-buffer reg-staged pipeline (no barriers, no asm):
    //   prologue: S<-tile0; LDS<-S; S<-tile1 (in flight).
    //   iter kt: ds_read+MFMA (tile kt) -> [LDS<-S (tile kt+1): WAR ok,
    //   in-order per-wave LDS; S<-tile kt+2] -> SEL (hides write latency).
    //   Compiler inserts vmcnt before WRITES and lgkmcnt before MFMAs.
    LOADS(0);
    WRITES();
    LOADS(1);

    for (int kt = 0; kt < 64; ++kt) {
        INIT128(acc);
        __builtin_amdgcn_s_setprio(1);
#pragma unroll
        for (int ks = 0; ks < 4; ++ks) {
            union { uint4 q[2]; i32x8 v; } b_;
            b_.q[0] = *(const uint4*)(Ws + bofs[ks][0]);
            b_.q[1] = *(const uint4*)(Ws + bofs[ks][1]);
            MFMA1(af[ks], b_);
        }
        __builtin_amdgcn_s_setprio(0);
        if (kt < 63) {
            WRITES();                       // LDS <- tile kt+1
            if (kt < 62) LOADS(kt + 2);     // S <- tile kt+2 (dense, 1 iter lead)
        }
        SEL16(acc, kt);
    }

    // merge: 32 rows x 256 keys = 32 KB (reuse Ws); first cross-wave flow
    __syncthreads();
    unsigned* ms = (unsigned*)Ws;
#pragma unroll
    for (int r = 0; r < 16; ++r) {
        int rloc = (r & 3) + 8 * (r >> 2) + 4 * h;
        *(uint2*)&ms[rloc * 256 + bcol * 2] = make_uint2(s0[r], s1[r]);
    }
    __syncthreads();
    if (tid < 32) {
        const uint4* rowk = (const uint4*)(ms + tid * 256);
        unsigned best[8];
#pragma unroll
        for (int i = 0; i < 8; ++i) best[i] = 0xFFFFFFFFu;
        for (int i = 0; i < 64; ++i) {
            uint4 qv = rowk[(i + tid) & 63];   // rotated: bank spread
            unsigned kk[4] = {qv.x, qv.y, qv.z, qv.w};
#pragma unroll
            for (int e = 0; e < 4; ++e) {
                unsigned key = kk[e];
                if (key < best[7]) {
                    best[7] = key;
#pragma unroll
                    for (int j = 7; j > 0; --j)
                        if (best[j] < best[j - 1]) {
                            unsigned t = best[j]; best[j] = best[j - 1]; best[j - 1] = t;
                        }
                }
            }
        }
        unsigned* out = cand + (size_t)(rowBase + tid) * 8;
#pragma unroll
        for (int i = 0; i < 8; ++i) out[i] = best[i];
    }
}

// ---------- exact rescore (fp32 chain, R3-verified) + inline numpy x2 ----------
__global__ __launch_bounds__(256) void vq_rescore_write(
    const float* __restrict__ x, const float* __restrict__ w,
    const float* __restrict__ wn, const unsigned* __restrict__ cand,
    float* __restrict__ outq, float* __restrict__ outi) {
    __shared__ int winners[32];
    const int tid = threadIdx.x;
    const int lr = tid >> 3, cc = tid & 7;
    const int row = blockIdx.x * 32 + lr;

    int k = (int)(cand[(size_t)row * 8 + cc] & 0x1FFFu);
    const float* xr = x + (size_t)row * DDIM;
    const float* wr = w + (size_t)k * DDIM;
    // dot: single fp32 fmaf chain d-ascending (BLAS-exact, R2/R3-verified)
    // x2: numpy pairwise (two halves, 8 stride-8 chains, exact nesting)
    float dot = 0.f;
    float half[2];
#pragma unroll
    for (int hh = 0; hh < 2; ++hh) {
        float r[8];
#pragma unroll
        for (int t = 0; t < 16; ++t) {
            const int d = hh * 128 + t * 8;
            float4 xa = *(const float4*)(xr + d);
            float4 xb = *(const float4*)(xr + d + 4);
            float4 wa = *(const float4*)(wr + d);
            float4 wb = *(const float4*)(wr + d + 4);
            dot = __fmaf_rn(xa.x, wa.x, dot); dot = __fmaf_rn(xa.y, wa.y, dot);
            dot = __fmaf_rn(xa.z, wa.z, dot); dot = __fmaf_rn(xa.w, wa.w, dot);
            dot = __fmaf_rn(xb.x, wb.x, dot); dot = __fmaf_rn(xb.y, wb.y, dot);
            dot = __fmaf_rn(xb.z, wb.z, dot); dot = __fmaf_rn(xb.w, wb.w, dot);
            if (t == 0) {
                r[0] = __fmul_rn(xa.x, xa.x); r[1] = __fmul_rn(xa.y, xa.y);
                r[2] = __fmul_rn(xa.z, xa.z); r[3] = __fmul_rn(xa.w, xa.w);
                r[4] = __fmul_rn(xb.x, xb.x); r[5] = __fmul_rn(xb.y, xb.y);
                r[6] = __fmul_rn(xb.z, xb.z); r[7] = __fmul_rn(xb.w, xb.w);
            } else {
                r[0] = __fadd_rn(r[0], __fmul_rn(xa.x, xa.x));
                r[1] = __fadd_rn(r[1], __fmul_rn(xa.y, xa.y));
                r[2] = __fadd_rn(r[2], __fmul_rn(xa.z, xa.z));
                r[3] = __fadd_rn(r[3], __fmul_rn(xa.w, xa.w));
                r[4] = __fadd_rn(r[4], __fmul_rn(xb.x, xb.x));
                r[5] = __fadd_rn(r[5], __fmul_rn(xb.y, xb.y));
                r[6] = __fadd_rn(r[6], __fmul_rn(xb.w == xb.w ? xb.z : xb.z, xb.z));
                r[7] = __fadd_rn(r[7], __fmul_rn(xb.w, xb.w));
            }
        }
        half[hh] = __fadd_rn(__fadd_rn(__fadd_rn(r[0], r[1]), __fadd_rn(r[2], r[3])),
                             __fadd_rn(__fadd_rn(r[4], r[5]), __fadd_rn(r[6], r[7])));
    }
    float x2v = __fadd_rn(half[0], half[1]);
    float dv = __fsub_rn(__fadd_rn(x2v, wn[k]), __fmul_rn(2.0f, dot));
    // lexicographic (dv,k) min across 8 candidate lanes (first-occurrence)
#pragma unroll
    for (int m = 1; m < 8; m <<= 1) {
        float od = __shfl_xor(dv, m, 64);
        int   ok = __shfl_xor(k,  m, 64);
        if (od < dv || (od == dv && ok < k)) { dv = od; k = ok; }
    }
    if (cc == 0) winners[lr] = k;
    __syncthreads();
    if (tid < 32) outi[blockIdx.x * 32 + tid] = (float)winners[tid];
    for (int u = tid; u < 32 * 64; u += 256) {
        int r = u >> 6, c4 = u & 63;
        *reinterpret_cast<float4*>(outq + (size_t)(blockIdx.x * 32 + r) * DDIM + c4 * 4) =
            *reinterpret_cast<const float4*>(w + (size_t)winners[r] * DDIM + c4 * 4);
    }
}

extern "C" void kernel_launch(void* const* d_in, const int* in_sizes, int n_in,
                              void* d_out, int out_size, void* d_ws, size_t ws_size,
                              hipStream_t stream) {
    const float* x = (const float*)d_in[0];
    const float* w = (const float*)d_in[1];
    const int N = in_sizes[0] / DDIM;   // 32768
    const int K = in_sizes[1] / DDIM;   // 8192
    float* outq = (float*)d_out;
    float* outi = outq + (size_t)N * DDIM;

    unsigned char* wb8 = (unsigned char*)d_ws;                // K*256 = 2 MB
    float* wn = (float*)(wb8 + (size_t)K * DDIM);             // K floats
    unsigned* cand = (unsigned*)(wn + K);                     // N*8 u32 = 1 MB

    hipLaunchKernelGGL(vq_prep_w, dim3(K / 32), dim3(256), 0, stream, w, wn, wb8);
    hipLaunchKernelGGL(vq_score, dim3(N / 32), dim3(256), 0, stream, x, wb8, cand);
    hipLaunchKernelGGL(vq_rescore_write, dim3(N / 32), dim3(256), 0, stream,
                       x, w, wn, cand, outq, outi);
}

// Round 13
// 276.796 us; speedup vs baseline: 3.1264x; 2.9486x over previous
//
#include <hip/hip_runtime.h>
#include <cfloat>

// VectorQuantizer: N=32768 rows, K=8192 codes, D=256, fp32.
// R2/R3 (absmax 0): reference = numpy fp32; exact top-8 rescore of approx
// candidates reproduces it bit-for-bit.
// R6 (125.3us score): 64-row LDS dbuf + syncthreads.               MfmaUtil 22.5
// R10 (119.4us): barrier-free counted-vmcnt (no cross-wave flow).  MfmaUtil 24
// R12 (117.7us): + deferred SEL + B reg-prefetch.                  MfmaUtil 24.5
//   => latency-bound at 2 waves/SIMD.
// R13-R19 scratch saga RESOLVED: the spills were never launch_bounds/occupancy
//   knobs. Pattern across 6 runs: uint4/union ARRAYS (bE[4], S[8]) -> scratch
//   (VGPR 80-84, 0.6-1.55GB WRITE) regardless of launch_bounds; NAMED vector
//   variables (R12 bA/bB, R14 a0..n3) -> clean regs (VGPR 108-124, WRITE
//   1024KB) even with PLAIN launch_bounds. Backend fails to promote aggregate
//   vector arrays (rule-20 sibling); scalar unsigned arrays are fine.
// R14 lesson kept: B via direct strided-global = TCP-serialized L2 latency;
//   B must be fetched dense-coalesced + LDS shuffle.
// R20 (this round): R15 pipeline with S[8] -> EIGHT NAMED uint4 (S0..S7),
//   plain __launch_bounds__(256) (R14-proven safe without arrays).
//   32-row blocks, grid 1024; single 32KB LDS buffer, reg-staged dense map,
//   barrier-free K-loop (per-wave private quarters + in-order LDS).
//   ~130 live regs -> 3 waves/SIMD; LDS 32KB -> 3 blocks/CU co-resident
//   = 12 waves/CU: the TLP experiment, finally unmasked.
//   Tripwires: WRITE_SIZE == 1024KB exactly, VGPR 100-140 (scratch again =>
//   array theory wrong => permanent revert to R12); success: dur 80-100us.
// prep_w / rescore untouched (bit-exact verified).

#define DDIM 256

typedef int   i32x8  __attribute__((ext_vector_type(8)));
typedef float f32x16 __attribute__((ext_vector_type(16)));

// ---------- W prep: numpy-exact ||w||^2 + negated scaled fp8 ----------
__global__ __launch_bounds__(256) void vq_prep_w(
    const float* __restrict__ w, float* __restrict__ wn,
    unsigned char* __restrict__ wb8) {
    __shared__ float rows[32 * 260];
    const int tid = threadIdx.x;
    const int r0 = blockIdx.x * 32;

    for (int idx = tid; idx < 32 * 64; idx += 256) {
        int r = idx >> 6, c4 = idx & 63;
        *(float4*)&rows[r * 260 + c4 * 4] =
            *(const float4*)(w + (size_t)(r0 + r) * DDIM + c4 * 4);
    }
    __syncthreads();
    {
        // numpy pairwise_sum(fl(a*a),256): two 128-halves, each 8 stride-8
        // chains, ((r0+r1)+(r2+r3))+((r4+r5)+(r6+r7)); shfl-xor == nesting.
        const int row = (tid >> 6) * 8 + ((tid & 63) >> 3), j = tid & 7;
        const float* a = &rows[row * 260];
        float half[2];
#pragma unroll
        for (int h = 0; h < 2; ++h) {
            const float* b = a + h * 128 + j;
            float r = __fmul_rn(b[0], b[0]);
#pragma unroll
            for (int t = 1; t < 16; ++t)
                r = __fadd_rn(r, __fmul_rn(b[8 * t], b[8 * t]));
            float p = __fadd_rn(r, __shfl_xor(r, 1, 64));
            p = __fadd_rn(p, __shfl_xor(p, 2, 64));
            p = __fadd_rn(p, __shfl_xor(p, 4, 64));
            half[h] = p;
        }
        if (j == 0) wn[r0 + row] = __fadd_rn(half[0], half[1]);
    }
    // fp8 e4m3 emission, scaled by -2^13 (pow2 cancels in argmin; negation
    // folds the "-2m" sign so acc = C - m_s with C=128 init)
    for (int idx = tid; idx < 32 * 16; idx += 256) {
        int r = idx >> 4, s = idx & 15;
        const float* p = &rows[r * 260 + s * 16];
        unsigned q[4];
#pragma unroll
        for (int m = 0; m < 4; ++m) {
            unsigned v = (unsigned)__builtin_amdgcn_cvt_pk_fp8_f32(
                p[m * 4 + 0] * -8192.f, p[m * 4 + 1] * -8192.f, 0, false);
            v = (unsigned)__builtin_amdgcn_cvt_pk_fp8_f32(
                p[m * 4 + 2] * -8192.f, p[m * 4 + 3] * -8192.f, (int)v, true);
            q[m] = v;
        }
        *(uint4*)(wb8 + (size_t)(r0 + r) * DDIM + s * 16) =
            make_uint4(q[0], q[1], q[2], q[3]);
    }
}

// ---------- MX-fp8 scorer: 32 rows x 8192 cols per block, 3 blocks/CU ----------
// 256 thr = 4 waves (wave = 32-col group); per wave per kt: 4-MFMA chain
// (ks over D=256). A resident in VGPRs. W tile 128c x 256d = 32KB, SINGLE
// LDS buffer, reg-staged (dense map, NAMED regs), barrier-free K-loop
// (per-wave private quarters + in-order LDS). LDS reused for the 32KB merge.
// C/D (32x32): col=lane&31, row=(reg&3)+8*(reg>>2)+4*(lane>>5)  [m74/m101].

#define INIT128(C) { _Pragma("unroll") for (int r_ = 0; r_ < 16; ++r_) (C)[r_] = 128.0f; }

// selection (R6-verbatim logic): acc = 128 - m_s > 0, uint-monotone;
// top-2 per (lane,reg) slot = code residue mod 128 per row.
#define SEL16(P, pkt) { \
    const unsigned colv_ = (unsigned)((pkt) * 128 + bcol); \
    _Pragma("unroll") for (int r_ = 0; r_ < 16; ++r_) { \
        unsigned key_ = (__float_as_uint((P)[r_]) & 0xFFFFE000u) | colv_; \
        unsigned a0_ = s0[r_]; \
        unsigned mx_ = key_ > a0_ ? key_ : a0_; \
        s1[r_] = mx_ < s1[r_] ? mx_ : s1[r_]; \
        s0[r_] = key_ < a0_ ? key_ : a0_; \
    } }

// dense-coalesced global loads of tile kt into NAMED registers (R6 map)
#define LOADS(kt) { \
    const unsigned char* g_ = wb8 + (size_t)(kt) * 32768; \
    S0 = *(const uint4*)(g_ + sOfs[0]); \
    S1 = *(const uint4*)(g_ + sOfs[1]); \
    S2 = *(const uint4*)(g_ + sOfs[2]); \
    S3 = *(const uint4*)(g_ + sOfs[3]); \
    S4 = *(const uint4*)(g_ + sOfs[4]); \
    S5 = *(const uint4*)(g_ + sOfs[5]); \
    S6 = *(const uint4*)(g_ + sOfs[6]); \
    S7 = *(const uint4*)(g_ + sOfs[7]); }

// NAMED registers -> LDS (each wave writes only its own 8KB quarter;
// i*1024 immediates fold into ds_write encodings)
#define WRITES() { \
    *(uint4*)(Ws + ldsBase + 0 * 1024) = S0; \
    *(uint4*)(Ws + ldsBase + 1 * 1024) = S1; \
    *(uint4*)(Ws + ldsBase + 2 * 1024) = S2; \
    *(uint4*)(Ws + ldsBase + 3 * 1024) = S3; \
    *(uint4*)(Ws + ldsBase + 4 * 1024) = S4; \
    *(uint4*)(Ws + ldsBase + 5 * 1024) = S5; \
    *(uint4*)(Ws + ldsBase + 6 * 1024) = S6; \
    *(uint4*)(Ws + ldsBase + 7 * 1024) = S7; }

#define MFMA1(A, B) \
    acc = __builtin_amdgcn_mfma_scale_f32_32x32x64_f8f6f4( \
        A, B.v, acc, 0, 0, 0, 0x7F7F7F7F, 0, 0x7F7F7F7F)

__global__ __launch_bounds__(256) void vq_score(
    const float* __restrict__ x, const unsigned char* __restrict__ wb8,
    unsigned* __restrict__ cand) {
    __shared__ __align__(16) unsigned char Ws[32768];
    const int tid = threadIdx.x;
    const int wave = tid >> 6, lane = tid & 63;
    const int h = lane >> 5, c32 = lane & 31;
    const int rowBase = blockIdx.x * 32;
    const int bcol = wave * 32 + c32;

    // A fragments: 32 rows x 256 dims fp8 (row = c32), converted in-kernel.
    i32x8 af[4];
    {
        const float* xr = x + (size_t)(rowBase + c32) * DDIM;
#pragma unroll
        for (int ks = 0; ks < 4; ++ks) {
            const float4* p = (const float4*)(xr + ks * 64 + h * 32);
            union { int d[8]; i32x8 v; } u;
#pragma unroll
            for (int m = 0; m < 8; ++m) {
                float4 f = p[m];
                unsigned v = (unsigned)__builtin_amdgcn_cvt_pk_fp8_f32(
                    f.x, f.y, 0, false);
                v = (unsigned)__builtin_amdgcn_cvt_pk_fp8_f32(
                    f.z, f.w, (int)v, true);
                u.d[m] = (int)v;
            }
            af[ks] = u.v;
        }
    }

    // staging maps (R6 VERBATIM, dense): slot covers 4 cols; granule XOR-
    // placed by col&15; wave w stages cols w*32..+31 = exactly its read cols.
    // Lane l writes granule g=(l&15)^(col&15) of col to byte col*256+(l&15)*16
    // => granule g sits at col*256+(g^(col&15))*16, matching bofs below.
    unsigned sOfs[8];
#pragma unroll
    for (int i = 0; i < 8; ++i) {
        int slot = wave * 8 + i;                  // 0..31
        int col  = slot * 4 + (lane >> 4);        // 0..127
        int gsrc = (lane & 15) ^ (col & 15);      // XOR bank spread
        sOfs[i] = (unsigned)(col * 256 + gsrc * 16);
    }
    const unsigned ldsBase = (unsigned)(wave * 8192 + (lane << 4));

    // B-fragment read offsets (R6 VERBATIM): granule gb of col bcol at
    // bcol*256 + (gb^(bcol&15))*16. Measured zero bank conflicts.
    const int cs = bcol & 15;
    int bofs[4][2];
#pragma unroll
    for (int ks = 0; ks < 4; ++ks) {
        int gb = ks * 4 + h * 2;
        bofs[ks][0] = bcol * 256 + ((gb)     ^ cs) * 16;
        bofs[ks][1] = bcol * 256 + ((gb + 1) ^ cs) * 16;
    }

    unsigned s0[16], s1[16];
#pragma unroll
    for (int r = 0; r < 16; ++r) { s0[r] = 0xFFFFFFFFu; s1[r] = 0xFFFFFFFFu; }

    f32x16 acc;
    uint4 S0, S1, S2, S3, S4, S5, S6, S7;   // NAMED staging regs (no array!)

    // Single-buffer reg-staged pipeline (no barriers, no asm):
    //   prologue: S<-tile0; LDS<-S; S<-tile1 (in flight).
    //   iter kt: ds_read+MFMA (tile kt) -> [LDS<-S (tile kt+1): WAR ok,
    //   in-order per-wave LDS; S<-tile kt+2] -> SEL (hides write latency).
    //   Compiler inserts vmcnt before WRITES and lgkmcnt before MFMAs.
    LOADS(0);
    WRITES();
    LOADS(1);

    for (int kt = 0; kt < 64; ++kt) {
        INIT128(acc);
        __builtin_amdgcn_s_setprio(1);
#pragma unroll
        for (int ks = 0; ks < 4; ++ks) {
            union { uint4 q[2]; i32x8 v; } b_;
            b_.q[0] = *(const uint4*)(Ws + bofs[ks][0]);
            b_.q[1] = *(const uint4*)(Ws + bofs[ks][1]);
            MFMA1(af[ks], b_);
        }
        __builtin_amdgcn_s_setprio(0);
        if (kt < 63) {
            WRITES();                       // LDS <- tile kt+1
            if (kt < 62) LOADS(kt + 2);     // S <- tile kt+2 (dense, 1 iter lead)
        }
        SEL16(acc, kt);
    }

    // merge: 32 rows x 256 keys = 32 KB (reuse Ws); first cross-wave flow
    __syncthreads();
    unsigned* ms = (unsigned*)Ws;
#pragma unroll
    for (int r = 0; r < 16; ++r) {
        int rloc = (r & 3) + 8 * (r >> 2) + 4 * h;
        *(uint2*)&ms[rloc * 256 + bcol * 2] = make_uint2(s0[r], s1[r]);
    }
    __syncthreads();
    if (tid < 32) {
        const uint4* rowk = (const uint4*)(ms + tid * 256);
        unsigned best[8];
#pragma unroll
        for (int i = 0; i < 8; ++i) best[i] = 0xFFFFFFFFu;
        for (int i = 0; i < 64; ++i) {
            uint4 qv = rowk[(i + tid) & 63];   // rotated: bank spread
            unsigned kk[4] = {qv.x, qv.y, qv.z, qv.w};
#pragma unroll
            for (int e = 0; e < 4; ++e) {
                unsigned key = kk[e];
                if (key < best[7]) {
                    best[7] = key;
#pragma unroll
                    for (int j = 7; j > 0; --j)
                        if (best[j] < best[j - 1]) {
                            unsigned t = best[j]; best[j] = best[j - 1]; best[j - 1] = t;
                        }
                }
            }
        }
        unsigned* out = cand + (size_t)(rowBase + tid) * 8;
#pragma unroll
        for (int i = 0; i < 8; ++i) out[i] = best[i];
    }
}

// ---------- exact rescore (fp32 chain, R3-verified) + inline numpy x2 ----------
__global__ __launch_bounds__(256) void vq_rescore_write(
    const float* __restrict__ x, const float* __restrict__ w,
    const float* __restrict__ wn, const unsigned* __restrict__ cand,
    float* __restrict__ outq, float* __restrict__ outi) {
    __shared__ int winners[32];
    const int tid = threadIdx.x;
    const int lr = tid >> 3, cc = tid & 7;
    const int row = blockIdx.x * 32 + lr;

    int k = (int)(cand[(size_t)row * 8 + cc] & 0x1FFFu);
    const float* xr = x + (size_t)row * DDIM;
    const float* wr = w + (size_t)k * DDIM;
    // dot: single fp32 fmaf chain d-ascending (BLAS-exact, R2/R3-verified)
    // x2: numpy pairwise (two halves, 8 stride-8 chains, exact nesting)
    float dot = 0.f;
    float half[2];
#pragma unroll
    for (int hh = 0; hh < 2; ++hh) {
        float r[8];
#pragma unroll
        for (int t = 0; t < 16; ++t) {
            const int d = hh * 128 + t * 8;
            float4 xa = *(const float4*)(xr + d);
            float4 xb = *(const float4*)(xr + d + 4);
            float4 wa = *(const float4*)(wr + d);
            float4 wb = *(const float4*)(wr + d + 4);
            dot = __fmaf_rn(xa.x, wa.x, dot); dot = __fmaf_rn(xa.y, wa.y, dot);
            dot = __fmaf_rn(xa.z, wa.z, dot); dot = __fmaf_rn(xa.w, wa.w, dot);
            dot = __fmaf_rn(xb.x, wb.x, dot); dot = __fmaf_rn(xb.y, wb.y, dot);
            dot = __fmaf_rn(xb.z, wb.z, dot); dot = __fmaf_rn(xb.w, wb.w, dot);
            if (t == 0) {
                r[0] = __fmul_rn(xa.x, xa.x); r[1] = __fmul_rn(xa.y, xa.y);
                r[2] = __fmul_rn(xa.z, xa.z); r[3] = __fmul_rn(xa.w, xa.w);
                r[4] = __fmul_rn(xb.x, xb.x); r[5] = __fmul_rn(xb.y, xb.y);
                r[6] = __fmul_rn(xb.z, xb.z); r[7] = __fmul_rn(xb.w, xb.w);
            } else {
                r[0] = __fadd_rn(r[0], __fmul_rn(xa.x, xa.x));
                r[1] = __fadd_rn(r[1], __fmul_rn(xa.y, xa.y));
                r[2] = __fadd_rn(r[2], __fmul_rn(xa.z, xa.z));
                r[3] = __fadd_rn(r[3], __fmul_rn(xa.w, xa.w));
                r[4] = __fadd_rn(r[4], __fmul_rn(xb.x, xb.x));
                r[5] = __fadd_rn(r[5], __fmul_rn(xb.y, xb.y));
                r[6] = __fadd_rn(r[6], __fmul_rn(xb.w == xb.w ? xb.z : xb.z, xb.z));
                r[7] = __fadd_rn(r[7], __fmul_rn(xb.w, xb.w));
            }
        }
        half[hh] = __fadd_rn(__fadd_rn(__fadd_rn(r[0], r[1]), __fadd_rn(r[2], r[3])),
                             __fadd_rn(__fadd_rn(r[4], r[5]), __fadd_rn(r[6], r[7])));
    }
    float x2v = __fadd_rn(half[0], half[1]);
    float dv = __fsub_rn(__fadd_rn(x2v, wn[k]), __fmul_rn(2.0f, dot));
    // lexicographic (dv,k) min across 8 candidate lanes (first-occurrence)
#pragma unroll
    for (int m = 1; m < 8; m <<= 1) {
        float od = __shfl_xor(dv, m, 64);
        int   ok = __shfl_xor(k,  m, 64);
        if (od < dv || (od == dv && ok < k)) { dv = od; k = ok; }
    }
    if (cc == 0) winners[lr] = k;
    __syncthreads();
    if (tid < 32) outi[blockIdx.x * 32 + tid] = (float)winners[tid];
    for (int u = tid; u < 32 * 64; u += 256) {
        int r = u >> 6, c4 = u & 63;
        *reinterpret_cast<float4*>(outq + (size_t)(blockIdx.x * 32 + r) * DDIM + c4 * 4) =
            *reinterpret_cast<const float4*>(w + (size_t)winners[r] * DDIM + c4 * 4);
    }
}

extern "C" void kernel_launch(void* const* d_in, const int* in_sizes, int n_in,
                              void* d_out, int out_size, void* d_ws, size_t ws_size,
                              hipStream_t stream) {
    const float* x = (const float*)d_in[0];
    const float* w = (const float*)d_in[1];
    const int N = in_sizes[0] / DDIM;   // 32768
    const int K = in_sizes[1] / DDIM;   // 8192
    float* outq = (float*)d_out;
    float* outi = outq + (size_t)N * DDIM;

    unsigned char* wb8 = (unsigned char*)d_ws;                // K*256 = 2 MB
    float* wn = (float*)(wb8 + (size_t)K * DDIM);             // K floats
    unsigned* cand = (unsigned*)(wn + K);                     // N*8 u32 = 1 MB

    hipLaunchKernelGGL(vq_prep_w, dim3(K / 32), dim3(256), 0, stream, w, wn, wb8);
    hipLaunchKernelGGL(vq_score, dim3(N / 32), dim3(256), 0, stream, x, wb8, cand);
    hipLaunchKernelGGL(vq_rescore_write, dim3(N / 32), dim3(256), 0, stream,
                       x, w, wn, cand, outq, outi);
}

// Round 14
// 250.728 us; speedup vs baseline: 3.4514x; 1.1040x over previous
//
#include <hip/hip_runtime.h>
#include <cfloat>

// VectorQuantizer: N=32768 rows, K=8192 codes, D=256, fp32.
// R2/R3 (absmax 0): reference = numpy fp32; exact top-8 rescore of approx
// candidates reproduces it bit-for-bit.
// SCORE history: R6 125.3 -> R10 119.4 (barrier-free counted-vmcnt) ->
//   R12 117.7 (deferred SEL + B reg-prefetch; VGPR 124, WRITE 1024KB, 0 confl).
//   R13-R19: spills = aggregate uint4 ARRAYS -> scratch (rule-20 sibling);
//   named vector vars -> clean. R14: strided-global B = TCP-serialized. R20:
//   32-row TLP test CLEAN (WRITE 1024KB) but 145us, MfmaUtil 20.5 -> TLP
//   FALSIFIED: halved per-iter MFMA density + doubled staging overhead loses.
//   => 64-row R12 structure is the right compute shape; score stays R12.
// R21 (this round): attack the OTHER 131us. total - score = 131us constant
//   across all rounds = prep(~10) + overhead(~15) + RESCORE (~90-110us).
//   Rescore redundancy: 8 candidate lanes each re-read the full 1KB x-row
//   (256KB/block, 8x redundant) + 256KB w-gather. Fix: stage 32 x-rows in
//   LDS once (260-float padded stride: 8-row groups hit banks 4r..4r+3,
//   8 same-row lanes broadcast -> zero conflicts), compute from LDS.
//   Bit-exact: identical fp32 values, identical op order.
// prep_w untouched (bit-exact verified).

#define DDIM 256

typedef int   i32x8  __attribute__((ext_vector_type(8)));
typedef float f32x16 __attribute__((ext_vector_type(16)));

// ---------- W prep: numpy-exact ||w||^2 + negated scaled fp8 ----------
__global__ __launch_bounds__(256) void vq_prep_w(
    const float* __restrict__ w, float* __restrict__ wn,
    unsigned char* __restrict__ wb8) {
    __shared__ float rows[32 * 260];
    const int tid = threadIdx.x;
    const int r0 = blockIdx.x * 32;

    for (int idx = tid; idx < 32 * 64; idx += 256) {
        int r = idx >> 6, c4 = idx & 63;
        *(float4*)&rows[r * 260 + c4 * 4] =
            *(const float4*)(w + (size_t)(r0 + r) * DDIM + c4 * 4);
    }
    __syncthreads();
    {
        // numpy pairwise_sum(fl(a*a),256): two 128-halves, each 8 stride-8
        // chains, ((r0+r1)+(r2+r3))+((r4+r5)+(r6+r7)); shfl-xor == nesting.
        const int row = (tid >> 6) * 8 + ((tid & 63) >> 3), j = tid & 7;
        const float* a = &rows[row * 260];
        float half[2];
#pragma unroll
        for (int h = 0; h < 2; ++h) {
            const float* b = a + h * 128 + j;
            float r = __fmul_rn(b[0], b[0]);
#pragma unroll
            for (int t = 1; t < 16; ++t)
                r = __fadd_rn(r, __fmul_rn(b[8 * t], b[8 * t]));
            float p = __fadd_rn(r, __shfl_xor(r, 1, 64));
            p = __fadd_rn(p, __shfl_xor(p, 2, 64));
            p = __fadd_rn(p, __shfl_xor(p, 4, 64));
            half[h] = p;
        }
        if (j == 0) wn[r0 + row] = __fadd_rn(half[0], half[1]);
    }
    // fp8 e4m3 emission, scaled by -2^13 (pow2 cancels in argmin; negation
    // folds the "-2m" sign so acc = C - m_s with C=128 init)
    for (int idx = tid; idx < 32 * 16; idx += 256) {
        int r = idx >> 4, s = idx & 15;
        const float* p = &rows[r * 260 + s * 16];
        unsigned q[4];
#pragma unroll
        for (int m = 0; m < 4; ++m) {
            unsigned v = (unsigned)__builtin_amdgcn_cvt_pk_fp8_f32(
                p[m * 4 + 0] * -8192.f, p[m * 4 + 1] * -8192.f, 0, false);
            v = (unsigned)__builtin_amdgcn_cvt_pk_fp8_f32(
                p[m * 4 + 2] * -8192.f, p[m * 4 + 3] * -8192.f, (int)v, true);
            q[m] = v;
        }
        *(uint4*)(wb8 + (size_t)(r0 + r) * DDIM + s * 16) =
            make_uint4(q[0], q[1], q[2], q[3]);
    }
}

// ---------- MX-fp8 scorer (R12 VERBATIM, 117.7us verified) ----------
// 64 rows x 8192 cols per block, 2 blocks/CU. 256 thr = 4 waves (wave =
// 32-col group); wave tile 64r x 32c = 2 MFMA 32x32x64 tiles. A resident in
// VGPRs. W 128c x 256k = 32KB tiles, 2 buffers, global_load_lds (16B),
// XOR-swizzled granules (ZERO bank conflicts). Barrier-free counted-vmcnt
// pipeline (no cross-wave data flow in K-loop); deferred selection; B
// register double-buffer.
// C/D (32x32): col=lane&31, row=(reg&3)+8*(reg>>2)+4*(lane>>5)  [m74/m101].

#define VWAIT(n) do { \
    asm volatile("s_waitcnt vmcnt(" #n ")" ::: "memory"); \
    __builtin_amdgcn_sched_barrier(0); \
  } while (0)

#define INIT128(C) { _Pragma("unroll") for (int r_ = 0; r_ < 16; ++r_) (C)[r_] = 128.0f; }

// deferred compare-update of 8 previous-kt keys (rows ks*4..ks*4+3, both rt).
#define SELCH(ks) { \
    _Pragma("unroll") for (int j_ = 0; j_ < 4; ++j_) { \
        const int r_ = (ks) * 4 + j_; \
        _Pragma("unroll") for (int rt_ = 0; rt_ < 2; ++rt_) { \
            unsigned key_ = pk[rt_][r_]; \
            unsigned a0_ = s0[rt_][r_]; \
            unsigned mx_ = key_ > a0_ ? key_ : a0_; \
            s1[rt_][r_] = mx_ < s1[rt_][r_] ? mx_ : s1[rt_][r_]; \
            s0[rt_][r_] = key_ < a0_ ? key_ : a0_; \
        } } }

// key extraction for THIS kt (depends on completed acc)
#define KEYX(pkt) { \
    const unsigned colv_ = (unsigned)((pkt) * 128 + bcol); \
    _Pragma("unroll") for (int r_ = 0; r_ < 16; ++r_) { \
        pk[0][r_] = (__float_as_uint(acc0[r_]) & 0xFFFFE000u) | colv_; \
        pk[1][r_] = (__float_as_uint(acc1[r_]) & 0xFFFFE000u) | colv_; \
    } }

// one ks step: prefetch next B pair, 2 MFMAs on current, deferred SEL chunk
#define STEP(ks, BC, BN, NK, TGL) do { \
    if (NK) { \
        BN.q[0] = *(const uint4*)(wsb + (TGL) + bofs[(ks) + 1][0]); \
        BN.q[1] = *(const uint4*)(wsb + (TGL) + bofs[(ks) + 1][1]); \
    } \
    acc0 = __builtin_amdgcn_mfma_scale_f32_32x32x64_f8f6f4( \
        af[0][ks], BC.v, acc0, 0, 0, 0, 0x7F7F7F7F, 0, 0x7F7F7F7F); \
    acc1 = __builtin_amdgcn_mfma_scale_f32_32x32x64_f8f6f4( \
        af[1][ks], BC.v, acc1, 0, 0, 0, 0x7F7F7F7F, 0, 0x7F7F7F7F); \
    SELCH(ks); \
  } while (0)

__global__ __launch_bounds__(256, 2) void vq_score(
    const float* __restrict__ x, const unsigned char* __restrict__ wb8,
    unsigned* __restrict__ cand) {
    __shared__ __align__(16) unsigned char Ws[2][32768];
    const int tid = threadIdx.x;
    const int wave = tid >> 6, lane = tid & 63;
    const int h = lane >> 5, c32 = lane & 31;
    const int rowBase = blockIdx.x * 64;
    const unsigned char* wsb = (const unsigned char*)&Ws[0][0];

    // A fragments: 64 rows x 256 k fp8, converted from fp32 global (one-time)
    i32x8 af[2][4];
#pragma unroll
    for (int rt = 0; rt < 2; ++rt) {
        const float* xr = x + (size_t)(rowBase + rt * 32 + c32) * DDIM;
#pragma unroll
        for (int ks = 0; ks < 4; ++ks) {
            const float4* p = (const float4*)(xr + ks * 64 + h * 32);
            union { int d[8]; i32x8 v; } u;
#pragma unroll
            for (int m = 0; m < 8; ++m) {
                float4 f = p[m];
                unsigned v = (unsigned)__builtin_amdgcn_cvt_pk_fp8_f32(
                    f.x, f.y, 0, false);
                v = (unsigned)__builtin_amdgcn_cvt_pk_fp8_f32(
                    f.z, f.w, (int)v, true);
                u.d[m] = (int)v;
            }
            af[rt][ks] = u.v;
        }
    }
    asm volatile("s_waitcnt vmcnt(0)" ::: "memory");

    // staging map (R6 VERBATIM): wave w stages slots w*8..w*8+7 = its own
    // read region -> no cross-wave flow in the K-loop.
    unsigned sOfs[8], ldsOfs[8];
#pragma unroll
    for (int i = 0; i < 8; ++i) {
        int slot = wave * 8 + i;                  // 0..31
        int col  = slot * 4 + (lane >> 4);        // 0..127
        int gsrc = (lane & 15) ^ (col & 15);      // XOR bank spread
        sOfs[i]   = (unsigned)(col * 256 + gsrc * 16);
        ldsOfs[i] = (unsigned)(slot * 1024);      // + lane*16 implicit
    }
    auto stage = [&](int kt, unsigned tgl) {
        const unsigned char* g = wb8 + (size_t)kt * 32768;
#pragma unroll
        for (int i = 0; i < 8; ++i)
            __builtin_amdgcn_global_load_lds(
                (const __attribute__((address_space(1))) unsigned int*)(g + sOfs[i]),
                (__attribute__((address_space(3))) unsigned int*)(
                    &Ws[0][0] + tgl + ldsOfs[i]),
                16, 0, 0);
    };

    const int bcol = wave * 32 + c32, cs = bcol & 15;
    int bofs[4][2];
#pragma unroll
    for (int ks = 0; ks < 4; ++ks) {
        int gb = ks * 4 + h * 2;
        bofs[ks][0] = bcol * 256 + ((gb)     ^ cs) * 16;
        bofs[ks][1] = bcol * 256 + ((gb + 1) ^ cs) * 16;
    }

    unsigned s0[2][16], s1[2][16], pk[2][16];
#pragma unroll
    for (int a = 0; a < 2; ++a)
#pragma unroll
        for (int r = 0; r < 16; ++r) {
            s0[a][r] = 0xFFFFFFFFu; s1[a][r] = 0xFFFFFFFFu; pk[a][r] = 0xFFFFFFFFu;
        }

    f32x16 acc0, acc1;
    union Bu { uint4 q[2]; i32x8 v; };
    Bu bA, bB;

    stage(0, 0);

    for (int kt = 0; kt < 63; ++kt) {
        const unsigned tgl = (unsigned)(kt & 1) << 15;
        stage(kt + 1, tgl ^ 32768u);
        INIT128(acc0); INIT128(acc1);
        VWAIT(8);
        bA.q[0] = *(const uint4*)(wsb + tgl + bofs[0][0]);
        bA.q[1] = *(const uint4*)(wsb + tgl + bofs[0][1]);
        __builtin_amdgcn_s_setprio(1);
        STEP(0, bA, bB, 1, tgl);
        STEP(1, bB, bA, 1, tgl);
        STEP(2, bA, bB, 1, tgl);
        STEP(3, bB, bA, 0, tgl);
        __builtin_amdgcn_s_setprio(0);
        KEYX(kt);
    }
    // kt = 63 (peeled tail)
    {
        INIT128(acc0); INIT128(acc1);
        VWAIT(0);
        bA.q[0] = *(const uint4*)(wsb + 32768 + bofs[0][0]);
        bA.q[1] = *(const uint4*)(wsb + 32768 + bofs[0][1]);
        __builtin_amdgcn_s_setprio(1);
        STEP(0, bA, bB, 1, 32768u);
        STEP(1, bB, bA, 1, 32768u);
        STEP(2, bA, bB, 1, 32768u);
        STEP(3, bB, bA, 0, 32768u);
        __builtin_amdgcn_s_setprio(0);
        KEYX(63);
        SELCH(0); SELCH(1); SELCH(2); SELCH(3);
    }

    // merge: 64 rows x 256 keys = 64 KB (reuse Ws)
    __syncthreads();
    unsigned* ms = (unsigned*)Ws;
#pragma unroll
    for (int rt = 0; rt < 2; ++rt)
#pragma unroll
        for (int r = 0; r < 16; ++r) {
            int rloc = rt * 32 + (r & 3) + 8 * (r >> 2) + 4 * h;
            *(uint2*)&ms[rloc * 256 + bcol * 2] = make_uint2(s0[rt][r], s1[rt][r]);
        }
    __syncthreads();
    if (tid < 64) {
        const uint4* rowk = (const uint4*)(ms + tid * 256);
        unsigned best[8];
#pragma unroll
        for (int i = 0; i < 8; ++i) best[i] = 0xFFFFFFFFu;
        for (int i = 0; i < 64; ++i) {
            uint4 qv = rowk[(i + tid) & 63];   // rotated: bank spread
            unsigned kk[4] = {qv.x, qv.y, qv.z, qv.w};
#pragma unroll
            for (int e = 0; e < 4; ++e) {
                unsigned key = kk[e];
                if (key < best[7]) {
                    best[7] = key;
#pragma unroll
                    for (int j = 7; j > 0; --j)
                        if (best[j] < best[j - 1]) {
                            unsigned t = best[j]; best[j] = best[j - 1]; best[j - 1] = t;
                        }
                }
            }
        }
        unsigned* out = cand + (size_t)(rowBase + tid) * 8;
#pragma unroll
        for (int i = 0; i < 8; ++i) out[i] = best[i];
    }
}

// ---------- exact rescore (fp32 chain, R3-verified) + inline numpy x2 ----------
// R21: x-rows staged in LDS once (8x traffic cut; 260-float padded stride ->
// zero bank conflicts, same-row lanes broadcast). Values/op-order identical.
__global__ __launch_bounds__(256) void vq_rescore_write(
    const float* __restrict__ x, const float* __restrict__ w,
    const float* __restrict__ wn, const unsigned* __restrict__ cand,
    float* __restrict__ outq, float* __restrict__ outi) {
    __shared__ float xrows[32 * 260];
    __shared__ int winners[32];
    const int tid = threadIdx.x;
    const int lr = tid >> 3, cc = tid & 7;
    const int row = blockIdx.x * 32 + lr;

    // cooperative coalesced stage of the block's 32 x-rows (1KB each)
    for (int idx = tid; idx < 32 * 64; idx += 256) {
        int r = idx >> 6, c4 = idx & 63;
        *(float4*)&xrows[r * 260 + c4 * 4] =
            *(const float4*)(x + (size_t)(blockIdx.x * 32 + r) * DDIM + c4 * 4);
    }
    __syncthreads();

    int k = (int)(cand[(size_t)row * 8 + cc] & 0x1FFFu);
    const float* xr = &xrows[lr * 260];
    const float* wr = w + (size_t)k * DDIM;
    // dot: single fp32 fmaf chain d-ascending (BLAS-exact, R2/R3-verified)
    // x2: numpy pairwise (two halves, 8 stride-8 chains, exact nesting)
    float dot = 0.f;
    float half[2];
#pragma unroll
    for (int hh = 0; hh < 2; ++hh) {
        float r[8];
#pragma unroll
        for (int t = 0; t < 16; ++t) {
            const int d = hh * 128 + t * 8;
            float4 xa = *(const float4*)(xr + d);
            float4 xb = *(const float4*)(xr + d + 4);
            float4 wa = *(const float4*)(wr + d);
            float4 wb = *(const float4*)(wr + d + 4);
            dot = __fmaf_rn(xa.x, wa.x, dot); dot = __fmaf_rn(xa.y, wa.y, dot);
            dot = __fmaf_rn(xa.z, wa.z, dot); dot = __fmaf_rn(xa.w, wa.w, dot);
            dot = __fmaf_rn(xb.x, wb.x, dot); dot = __fmaf_rn(xb.y, wb.y, dot);
            dot = __fmaf_rn(xb.z, wb.z, dot); dot = __fmaf_rn(xb.w, wb.w, dot);
            if (t == 0) {
                r[0] = __fmul_rn(xa.x, xa.x); r[1] = __fmul_rn(xa.y, xa.y);
                r[2] = __fmul_rn(xa.z, xa.z); r[3] = __fmul_rn(xa.w, xa.w);
                r[4] = __fmul_rn(xb.x, xb.x); r[5] = __fmul_rn(xb.y, xb.y);
                r[6] = __fmul_rn(xb.z, xb.z); r[7] = __fmul_rn(xb.w, xb.w);
            } else {
                r[0] = __fadd_rn(r[0], __fmul_rn(xa.x, xa.x));
                r[1] = __fadd_rn(r[1], __fmul_rn(xa.y, xa.y));
                r[2] = __fadd_rn(r[2], __fmul_rn(xa.z, xa.z));
                r[3] = __fadd_rn(r[3], __fmul_rn(xa.w, xa.w));
                r[4] = __fadd_rn(r[4], __fmul_rn(xb.x, xb.x));
                r[5] = __fadd_rn(r[5], __fmul_rn(xb.y, xb.y));
                r[6] = __fadd_rn(r[6], __fmul_rn(xb.w == xb.w ? xb.z : xb.z, xb.z));
                r[7] = __fadd_rn(r[7], __fmul_rn(xb.w, xb.w));
            }
        }
        half[hh] = __fadd_rn(__fadd_rn(__fadd_rn(r[0], r[1]), __fadd_rn(r[2], r[3])),
                             __fadd_rn(__fadd_rn(r[4], r[5]), __fadd_rn(r[6], r[7])));
    }
    float x2v = __fadd_rn(half[0], half[1]);
    float dv = __fsub_rn(__fadd_rn(x2v, wn[k]), __fmul_rn(2.0f, dot));
    // lexicographic (dv,k) min across 8 candidate lanes (first-occurrence)
#pragma unroll
    for (int m = 1; m < 8; m <<= 1) {
        float od = __shfl_xor(dv, m, 64);
        int   ok = __shfl_xor(k,  m, 64);
        if (od < dv || (od == dv && ok < k)) { dv = od; k = ok; }
    }
    if (cc == 0) winners[lr] = k;
    __syncthreads();
    if (tid < 32) outi[blockIdx.x * 32 + tid] = (float)winners[tid];
    for (int u = tid; u < 32 * 64; u += 256) {
        int r = u >> 6, c4 = u & 63;
        *reinterpret_cast<float4*>(outq + (size_t)(blockIdx.x * 32 + r) * DDIM + c4 * 4) =
            *reinterpret_cast<const float4*>(w + (size_t)winners[r] * DDIM + c4 * 4);
    }
}

extern "C" void kernel_launch(void* const* d_in, const int* in_sizes, int n_in,
                              void* d_out, int out_size, void* d_ws, size_t ws_size,
                              hipStream_t stream) {
    const float* x = (const float*)d_in[0];
    const float* w = (const float*)d_in[1];
    const int N = in_sizes[0] / DDIM;   // 32768
    const int K = in_sizes[1] / DDIM;   // 8192
    float* outq = (float*)d_out;
    float* outi = outq + (size_t)N * DDIM;

    unsigned char* wb8 = (unsigned char*)d_ws;                // K*256 = 2 MB
    float* wn = (float*)(wb8 + (size_t)K * DDIM);             // K floats
    unsigned* cand = (unsigned*)(wn + K);                     // N*8 u32 = 1 MB

    hipLaunchKernelGGL(vq_prep_w, dim3(K / 32), dim3(256), 0, stream, w, wn, wb8);
    hipLaunchKernelGGL(vq_score, dim3(N / 64), dim3(256), 0, stream, x, wb8, cand);
    hipLaunchKernelGGL(vq_rescore_write, dim3(N / 32), dim3(256), 0, stream,
                       x, w, wn, cand, outq, outi);
}